// Round 10
// baseline (188.548 us; speedup 1.0000x reference)
//
#include <hip/hip_runtime.h>
#include <hip/hip_bf16.h>

#define DM 1024
#define NH 16
#define DK 64
#define TT 2048
#define NBATCH 4
#define BT 8192   // NBATCH*TT

typedef __attribute__((ext_vector_type(8))) short short8;
typedef __attribute__((ext_vector_type(4))) float f32x4;
typedef unsigned short u16;

#define MFMA(a,b,c) __builtin_amdgcn_mfma_f32_16x16x32_bf16((a),(b),(c),0,0,0)

// 1/sqrt(64) * log2(e): folded into Q so attn softmax can use exp2 directly
#define QSCALE 0.18033688011112684f

// raw v_exp_f32 (flush-denorm fine for softmax), skips OCML fixup code
#define EXP2(x) __builtin_amdgcn_exp2f(x)

__device__ __forceinline__ u16 f2bf(float f){
  union { float f; unsigned u; } v; v.f = f;
  return (u16)((v.u + 0x7fffu + ((v.u >> 16) & 1u)) >> 16);
}

__device__ __forceinline__ unsigned cvtpk(float lo, float hi){
  unsigned r;
  asm("v_cvt_pk_bf16_f32 %0, %1, %2" : "=v"(r) : "v"(lo), "v"(hi));
  return r;
}

// async global->LDS DMA, 16B/lane. LDS dest must be wave-uniform base (+lane*16).
__device__ __forceinline__ void gload16(const void* g, void* l){
  __builtin_amdgcn_global_load_lds((__attribute__((address_space(1))) void*)(g),
                                   (__attribute__((address_space(3))) void*)(l), 16, 0, 0);
}

// cross-lane reduce over the 4 16-lane groups (lane ^16, ^32): pure-VALU permlanes
__device__ __forceinline__ float plmax(float x){
#if __has_builtin(__builtin_amdgcn_permlane16_swap) && __has_builtin(__builtin_amdgcn_permlane32_swap)
  auto r = __builtin_amdgcn_permlane16_swap(__float_as_uint(x), __float_as_uint(x), false, false);
  x = fmaxf(__uint_as_float(r[0]), __uint_as_float(r[1]));
  auto r2 = __builtin_amdgcn_permlane32_swap(__float_as_uint(x), __float_as_uint(x), false, false);
  x = fmaxf(__uint_as_float(r2[0]), __uint_as_float(r2[1]));
#else
  x = fmaxf(x, __shfl_xor(x, 16, 64));
  x = fmaxf(x, __shfl_xor(x, 32, 64));
#endif
  return x;
}

__device__ __forceinline__ float plsum(float x){
#if __has_builtin(__builtin_amdgcn_permlane16_swap) && __has_builtin(__builtin_amdgcn_permlane32_swap)
  auto r = __builtin_amdgcn_permlane16_swap(__float_as_uint(x), __float_as_uint(x), false, false);
  x = __uint_as_float(r[0]) + __uint_as_float(r[1]);
  auto r2 = __builtin_amdgcn_permlane32_swap(__float_as_uint(x), __float_as_uint(x), false, false);
  x = __uint_as_float(r2[0]) + __uint_as_float(r2[1]);
#else
  x = x + __shfl_xor(x, 16, 64);
  x = x + __shfl_xor(x, 32, 64);
#endif
  return x;
}

// ---------------- x fp32 -> bf16 ----------------
__global__ __launch_bounds__(256) void cvt_x(const float* __restrict__ x, u16* __restrict__ xb){
  int i = (blockIdx.x * 256 + threadIdx.x) * 4;
  float4 v = *(const float4*)(x + i);
  u16 o0 = f2bf(v.x), o1 = f2bf(v.y), o2 = f2bf(v.z), o3 = f2bf(v.w);
  ushort4 o; o.x=o0; o.y=o1; o.z=o2; o.w=o3;
  *(ushort4*)(xb + i) = o;
}

// ---------------- W (K,N) fp32 -> wt (N,K) bf16, all 3 mats in one launch ----------------
__global__ __launch_bounds__(256) void twp(
    const float* __restrict__ Wq, const float* __restrict__ Wk, const float* __restrict__ Wv,
    u16* __restrict__ wtq, u16* __restrict__ wtk, u16* __restrict__ wtv){
  const float* W = (blockIdx.z == 0) ? Wq : (blockIdx.z == 1) ? Wk : Wv;
  u16* wt = (blockIdx.z == 0) ? wtq : (blockIdx.z == 1) ? wtk : wtv;
  __shared__ float tile[32][33];
  int k0 = blockIdx.x * 32, n0 = blockIdx.y * 32;
  int tx = threadIdx.x & 31, ty = threadIdx.x >> 5;
  #pragma unroll
  for(int r = ty; r < 32; r += 8)
    tile[r][tx] = W[(size_t)(k0 + r) * DM + n0 + tx];
  __syncthreads();
  #pragma unroll
  for(int r = ty; r < 32; r += 8)
    wt[(size_t)(n0 + r) * DM + k0 + tx] = f2bf(tile[tx][r]);
}

// ---------------- QKV projection GEMM: A direct-from-L2, B LDS-staged ----------------
// qkv was ~81% LDS-BW-bound (R6 accounting: 750 cyc LDS service of 1845-cyc wall).
// A's per-XCD working set is 2MB = L2-resident (XCD-stripe swizzle), so A-frags
// load DIRECT global->register (b128, 64B/row/wave-iter), register-double-buffered:
// next tile's loads issue right after the barrier, drained at the NEXT barrier.
// B keeps LDS staging (24x panel reuse). LDS service halves (48KB -> ~375cyc),
// LDS 64->32KB. B: linear DMA dest + inverse-swizzled source + XOR read (rule 21).
// V^T store KEY-PERMUTED (attn PV: key 16*hi+4*g+r -> pos 8*g+4*hi+r).
__global__ __launch_bounds__(256) void qkv_gemm(
    const u16* __restrict__ xb,
    const u16* __restrict__ wtq, const u16* __restrict__ wtk, const u16* __restrict__ wtv,
    const float* __restrict__ bq, const float* __restrict__ bk, const float* __restrict__ bv,
    u16* __restrict__ qws, u16* __restrict__ kws, u16* __restrict__ vtws){
  __shared__ u16 sb[2][128 * 64];
  const int id = blockIdx.x;              // 0..1535
  const int idx = id >> 3;                // 0..191 within XCD
  const int mt = (id & 7) * 8 + (idx & 7);// M-tile 0..63
  const int y  = idx >> 3;                // weight panel 0..23
  const int m0 = mt * 128;
  const int ng = y * 128;
  const int mat = ng >> 10;
  const int n0 = ng & 1023;
  const u16* wt = (mat == 0) ? wtq : (mat == 1) ? wtk : wtv;
  const float* bias = (mat == 0) ? bq : (mat == 1) ? bk : bv;
  const int tid = threadIdx.x;
  const int lane = tid & 63, w = tid >> 6;
  const int ln16 = lane & 15, hi = lane >> 4;
  const int wm = (w >> 1) * 64, wn = (w & 1) * 64;
  const int wbase0 = tid & 192;   // w*64, wave-uniform

  // per-lane A base: row m0+wm+ln16, k-slot hi*8 (elements)
  const u16* xA = xb + (size_t)(m0 + wm + ln16) * 1024 + hi * 8;

  f32x4 acc[4][4] = {};
  short8 afc[4][2], afn[4][2];

  // prologue: stage B tile 0 -> buf 0 (async DMA); load A frags tile 0 to regs
  #pragma unroll
  for(int p = 0; p < 4; p++){
    int base = p * 256 + wbase0;
    int idx2 = base + lane;
    int row = idx2 >> 3;
    int chs = (idx2 & 7) ^ (row & 7);
    gload16(wt + (size_t)(n0 + row) * 1024 + chs * 8, (char*)sb[0] + base * 16);
  }
  #pragma unroll
  for(int i = 0; i < 4; i++)
    #pragma unroll
    for(int ks = 0; ks < 2; ks++)
      afc[i][ks] = *(const short8*)(xA + (size_t)(i * 16) * 1024 + ks * 32);

  #pragma unroll 2
  for(int kt = 0; kt < 16; kt++){
    const int cur = kt & 1;
    __syncthreads();               // drains vmcnt: sb[cur] + afc ready; sb[cur^1] readers done

    if(kt + 1 < 16){
      const int k0n = (kt + 1) * 64;
      // B DMA for kt+1 into the just-freed buffer
      #pragma unroll
      for(int p = 0; p < 4; p++){
        int base = p * 256 + wbase0;
        int idx2 = base + lane;
        int row = idx2 >> 3;
        int chs = (idx2 & 7) ^ (row & 7);
        gload16(wt + (size_t)(n0 + row) * 1024 + k0n + chs * 8, (char*)sb[cur ^ 1] + base * 16);
      }
      // A frags for kt+1 -> afn (in flight through this iter's MFMA phase)
      #pragma unroll
      for(int i = 0; i < 4; i++)
        #pragma unroll
        for(int ks = 0; ks < 2; ks++)
          afn[i][ks] = *(const short8*)(xA + (size_t)(i * 16) * 1024 + k0n + ks * 32);
    }

    #pragma unroll
    for(int ks = 0; ks < 2; ks++){
      short8 bfr[4];
      #pragma unroll
      for(int i = 0; i < 4; i++){
        int rb = wn + i * 16 + ln16;
        int ca = ks * 64 + hi * 16;
        bfr[i] = *(const short8*)((const char*)sb[cur] + rb * 128 + (ca ^ ((rb & 7) << 4)));
      }
      __builtin_amdgcn_s_setprio(1);
      #pragma unroll
      for(int i = 0; i < 4; i++)
        #pragma unroll
        for(int j = 0; j < 4; j++)
          acc[i][j] = MFMA(afc[i][ks], bfr[j], acc[i][j]);
      __builtin_amdgcn_s_setprio(0);
    }

    if(kt + 1 < 16){
      #pragma unroll
      for(int i = 0; i < 4; i++)
        #pragma unroll
        for(int ks = 0; ks < 2; ks++)
          afc[i][ks] = afn[i][ks];
    }
  }

  const float scl = (mat == 0) ? QSCALE : 1.0f;
  #pragma unroll
  for(int j = 0; j < 4; j++){
    int n = n0 + wn + j * 16 + ln16;
    float bv_ = bias[n];
    int h = n >> 6, d = n & 63;
    #pragma unroll
    for(int i = 0; i < 4; i++){
      int mb = m0 + wm + i * 16 + hi * 4;
      int b = mb >> 11, t = mb & 2047;
      int bh = b * NH + h;
      if(mat == 2){
        // V^T store, KEY-PERMUTED within each 32-key group (attn PV b128 reads)
        ushort4 o4;
        o4.x = f2bf(acc[i][j][0] + bv_);
        o4.y = f2bf(acc[i][j][1] + bv_);
        o4.z = f2bf(acc[i][j][2] + bv_);
        o4.w = f2bf(acc[i][j][3] + bv_);
        int tp = (t & ~31) | (((t >> 2) & 3) << 3) | (((t >> 4) & 1) << 2);
        *(ushort4*)(vtws + ((size_t)bh * DK + d) * TT + tp) = o4;
      } else {
        u16* dst = (mat == 0) ? qws : kws;
        #pragma unroll
        for(int r = 0; r < 4; r++){
          u16 o = f2bf((acc[i][j][r] + bv_) * scl);
          dst[((size_t)bh * TT + t + r) * DK + d] = o;
        }
      }
    }
  }
}

// ---------------- flash attention (R6-verified: 8-wave, paired, 16 waves/CU) ----------------
// 8-wave blocks, 128 q-rows per q-tile; per-tile fixed costs amortized over 2x
// q-rows. Grid 512, bijective XCD swizzle (XCD k owns bh in [8k,8k+8), 4MB = its
// L2); pairs (x, 15-x) -> every block runs exactly 34 k-iterations (balanced —
// R2/R9 lesson: imbalance poisons occupancy). 2 blocks/CU x 8 waves = 16
// waves/CU. Lower 4 waves skip their fully-masked final k-tile. VGPR ~56 (< 64
// cliff). At ~97% of the LDS-service model — attn structural ceiling.
__global__ __launch_bounds__(512) void attn(
    const u16* __restrict__ qws, const u16* __restrict__ kws, const u16* __restrict__ vtws,
    float* __restrict__ out){
  __shared__ u16 kt[2][64 * 64];    // [buf][key][d]  swizzled
  __shared__ u16 vt[2][64 * 64];    // [buf][d][key-permuted]  swizzled

  const int id = blockIdx.x;
  const int swz = (id & 7) * 64 + (id >> 3);   // bijective (512 % 8 == 0)
  const int qx = swz & 7;                      // pair index 0..7
  const int bh = swz >> 3;

  const int tid = threadIdx.x, lane = tid & 63, w = tid >> 6;   // w 0..7
  const int g = lane >> 4, ln = lane & 15;
  const int b = bh >> 4, h = bh & 15;
  const u16* kbase = kws + (size_t)bh * TT * DK;
  const u16* vbase = vtws + (size_t)bh * DK * TT;
  const int sbase = tid & 448;      // wave-uniform 16B-chunk base (HW adds lane*16)
  const int srow = tid >> 3;        // staging row 0..63
  const int schs = (tid & 7) ^ (srow & 7);     // inverse swizzle on the SOURCE

  #pragma unroll 1
  for(int qi = 0; qi < 2; qi++){
    const int qt = qi ? (15 - qx) : qx;        // 128-row q-tile 0..15
    const int q = qt * 128 + w * 16 + ln;      // this lane's q row

    // Q fragment (B-operand; pre-scaled by QSCALE): k-slots d = g*8+j (+32)
    short8 qf[2];
    {
      const u16* gq = qws + ((size_t)bh * TT + q) * DK + g * 8;
      qf[0] = *(const short8*)gq;
      qf[1] = *(const short8*)(gq + 32);
    }

    f32x4 o[4] = {};                 // O^T frags: o[i][r] = O^T[d=i*16+g*4+r][q]
    float m = -INFINITY, l = 0.f;    // l: per-lane partial sum (reduced in epilogue)

    const int nkt = 2 * qt + 2;            // block-level 64-key tiles
    const int myNkt = nkt - (w < 4 ? 1 : 0);  // lower waves: last tile fully masked

    __syncthreads();                 // prev q-tile readers done; no DMAs outstanding
    // stage k-tile 0 -> buf 0 (async DMA; 512 threads cover 64x64 in one pass)
    gload16(kbase + (size_t)srow * DK + schs * 8, (char*)kt[0] + sbase * 16);
    gload16(vbase + (size_t)srow * TT + schs * 8, (char*)vt[0] + sbase * 16);

    #pragma unroll 1
    for(int kti = 0; kti < nkt; kti++){
      const int cur = kti & 1;
      __syncthreads();               // drains vmcnt: buf[cur] ready; buf[cur^1] readers done

      // async-prefetch next tile straight into buf[cur^1] (drained at next barrier)
      if(kti + 1 < nkt){
        const int k0n = (kti + 1) * 64;
        gload16(kbase + (size_t)(k0n + srow) * DK + schs * 8, (char*)kt[cur ^ 1] + sbase * 16);
        gload16(vbase + (size_t)srow * TT + k0n + schs * 8, (char*)vt[cur ^ 1] + sbase * 16);
      }

      if(kti < myNkt){
        // S^T = K Q : s[i][r] = S[key = k0+i*16+g*4+r][q]
        f32x4 s[4];
        __builtin_amdgcn_s_setprio(1);
        #pragma unroll
        for(int i = 0; i < 4; i++){
          f32x4 c = {};
          #pragma unroll
          for(int ks = 0; ks < 2; ks++){
            int rb = i * 16 + ln;
            int cb = ks * 64 + g * 16;
            short8 kfr = *(const short8*)((const char*)kt[cur] + rb * 128 + (cb ^ ((rb & 7) << 4)));
            c = MFMA(kfr, qf[ks], c);
          }
          s[i] = c;
        }
        __builtin_amdgcn_s_setprio(0);

        if(kti == myNkt - 1){          // causal mask (this wave's diagonal tile)
          const int k0 = kti * 64;
          #pragma unroll
          for(int i = 0; i < 4; i++)
            #pragma unroll
            for(int r = 0; r < 4; r++)
              if(k0 + i * 16 + g * 4 + r > q) s[i][r] = -INFINITY;
        }

        // in-register row max (16 regs) + cross-group permlane swaps (full row = 4 groups)
        float mx0 = fmaxf(fmaxf(s[0][0], s[0][1]), fmaxf(s[0][2], s[0][3]));
        float mx1 = fmaxf(fmaxf(s[1][0], s[1][1]), fmaxf(s[1][2], s[1][3]));
        float mx2 = fmaxf(fmaxf(s[2][0], s[2][1]), fmaxf(s[2][2], s[2][3]));
        float mx3 = fmaxf(fmaxf(s[3][0], s[3][1]), fmaxf(s[3][2], s[3][3]));
        float pmax = fmaxf(fmaxf(mx0, mx1), fmaxf(mx2, mx3));
        pmax = plmax(pmax);

        // defer-max (T13): skip O-rescale when per-tile max growth <= 8 (exp2 domain)
        if(!__all(pmax <= m + 8.f)){
          float mnew = fmaxf(m, pmax);
          float alpha = EXP2(m - mnew);
          l *= alpha;
          #pragma unroll
          for(int i = 0; i < 4; i++)
            #pragma unroll
            for(int r = 0; r < 4; r++) o[i][r] *= alpha;
          m = mnew;
        }

        #pragma unroll
        for(int i = 0; i < 4; i++)
          #pragma unroll
          for(int r = 0; r < 4; r++){
            float p = EXP2(s[i][r] - m);
            s[i][r] = p; l += p;        // per-lane partial only
          }

        // pack P to bf16 B-frags in-register: pb[ks] reg j holds key kappa(g,j)+32ks
        union PU { short8 s8; unsigned w[4]; };
        PU pb[2];
        #pragma unroll
        for(int ks = 0; ks < 2; ks++){
          pb[ks].w[0] = cvtpk(s[2*ks][0],   s[2*ks][1]);
          pb[ks].w[1] = cvtpk(s[2*ks][2],   s[2*ks][3]);
          pb[ks].w[2] = cvtpk(s[2*ks+1][0], s[2*ks+1][1]);
          pb[ks].w[3] = cvtpk(s[2*ks+1][2], s[2*ks+1][3]);
        }

        // O^T += V^T P^T : key-permuted vt makes each A-frag ONE swizzled b128 read
        __builtin_amdgcn_s_setprio(1);
        #pragma unroll
        for(int i = 0; i < 4; i++){
          int dr = i * 16 + ln;
          const char* vrow = (const char*)vt[cur] + dr * 128;
          int sw = (dr & 7) << 4;
          #pragma unroll
          for(int ks = 0; ks < 2; ks++){
            short8 av = *(const short8*)(vrow + ((64 * ks + g * 16) ^ sw));
            o[i] = MFMA(av, pb[ks].s8, o[i]);
          }
        }
        __builtin_amdgcn_s_setprio(0);
      }
    }

    // epilogue: deferred l reduce, then out (B,T,DM) fp32, float4 stores
    l = plsum(l);
    float inv = 1.0f / l;
    float* orow = out + ((size_t)(b * TT + q)) * DM + h * 64 + g * 4;
    #pragma unroll
    for(int i = 0; i < 4; i++){
      float4 v4;
      v4.x = o[i][0] * inv; v4.y = o[i][1] * inv;
      v4.z = o[i][2] * inv; v4.w = o[i][3] * inv;
      *(float4*)(orow + i * 16) = v4;
    }
  }
}

extern "C" void kernel_launch(void* const* d_in, const int* in_sizes, int n_in,
                              void* d_out, int out_size, void* d_ws, size_t ws_size,
                              hipStream_t stream){
  const float* x  = (const float*)d_in[0];
  const float* Wq = (const float*)d_in[1];
  const float* bq = (const float*)d_in[2];
  const float* Wk = (const float*)d_in[3];
  const float* bk = (const float*)d_in[4];
  const float* Wv = (const float*)d_in[5];
  const float* bv = (const float*)d_in[6];
  float* out = (float*)d_out;

  char* ws = (char*)d_ws;
  u16* xb   = (u16*)(ws);                       // 16 MB  x bf16 (M,K)
  u16* wtq  = (u16*)(ws + (16u << 20));         //  2 MB  Wq^T bf16 (N,K)
  u16* wtk  = (u16*)(ws + (18u << 20));
  u16* wtv  = (u16*)(ws + (20u << 20));
  u16* qws  = (u16*)(ws + (22u << 20));         // 16 MB  Q (BH,T,DK) bf16 (pre-scaled)
  u16* kws  = (u16*)(ws + (38u << 20));         // 16 MB  K (BH,T,DK) bf16
  u16* vtws = (u16*)(ws + (54u << 20));         // 16 MB  V^T (BH,DK,T) bf16, key-permuted

  cvt_x<<<dim3(BT * DM / 1024), dim3(256), 0, stream>>>(x, xb);
  twp<<<dim3(32, 32, 3), dim3(256), 0, stream>>>(Wq, Wk, Wv, wtq, wtk, wtv);
  qkv_gemm<<<dim3(1536), dim3(256), 0, stream>>>(xb, wtq, wtk, wtv, bq, bk, bv, qws, kws, vtws);
  attn<<<dim3(512), dim3(512), 0, stream>>>(qws, kws, vtws, out);
}

// Round 11
// 141.297 us; speedup vs baseline: 1.3344x; 1.3344x over previous
//
#include <hip/hip_runtime.h>
#include <hip/hip_bf16.h>

#define DM 1024
#define NH 16
#define DK 64
#define TT 2048
#define NBATCH 4
#define BT 8192   // NBATCH*TT

typedef __attribute__((ext_vector_type(8))) short short8;
typedef __attribute__((ext_vector_type(4))) float f32x4;
typedef unsigned short u16;

#define MFMA(a,b,c) __builtin_amdgcn_mfma_f32_16x16x32_bf16((a),(b),(c),0,0,0)

// 1/sqrt(64) * log2(e): folded into Q so attn softmax can use exp2 directly
#define QSCALE 0.18033688011112684f

// raw v_exp_f32 (flush-denorm fine for softmax), skips OCML fixup code
#define EXP2(x) __builtin_amdgcn_exp2f(x)

__device__ __forceinline__ u16 f2bf(float f){
  union { float f; unsigned u; } v; v.f = f;
  return (u16)((v.u + 0x7fffu + ((v.u >> 16) & 1u)) >> 16);
}

__device__ __forceinline__ unsigned cvtpk(float lo, float hi){
  unsigned r;
  asm("v_cvt_pk_bf16_f32 %0, %1, %2" : "=v"(r) : "v"(lo), "v"(hi));
  return r;
}

// async global->LDS DMA, 16B/lane. LDS dest must be wave-uniform base (+lane*16).
__device__ __forceinline__ void gload16(const void* g, void* l){
  __builtin_amdgcn_global_load_lds((__attribute__((address_space(1))) void*)(g),
                                   (__attribute__((address_space(3))) void*)(l), 16, 0, 0);
}

// cross-lane reduce over the 4 16-lane groups (lane ^16, ^32): pure-VALU permlanes
__device__ __forceinline__ float plmax(float x){
#if __has_builtin(__builtin_amdgcn_permlane16_swap) && __has_builtin(__builtin_amdgcn_permlane32_swap)
  auto r = __builtin_amdgcn_permlane16_swap(__float_as_uint(x), __float_as_uint(x), false, false);
  x = fmaxf(__uint_as_float(r[0]), __uint_as_float(r[1]));
  auto r2 = __builtin_amdgcn_permlane32_swap(__float_as_uint(x), __float_as_uint(x), false, false);
  x = fmaxf(__uint_as_float(r2[0]), __uint_as_float(r2[1]));
#else
  x = fmaxf(x, __shfl_xor(x, 16, 64));
  x = fmaxf(x, __shfl_xor(x, 32, 64));
#endif
  return x;
}

__device__ __forceinline__ float plsum(float x){
#if __has_builtin(__builtin_amdgcn_permlane16_swap) && __has_builtin(__builtin_amdgcn_permlane32_swap)
  auto r = __builtin_amdgcn_permlane16_swap(__float_as_uint(x), __float_as_uint(x), false, false);
  x = __uint_as_float(r[0]) + __uint_as_float(r[1]);
  auto r2 = __builtin_amdgcn_permlane32_swap(__float_as_uint(x), __float_as_uint(x), false, false);
  x = __uint_as_float(r2[0]) + __uint_as_float(r2[1]);
#else
  x = x + __shfl_xor(x, 16, 64);
  x = x + __shfl_xor(x, 32, 64);
#endif
  return x;
}

// ---------------- prep: x fp32->bf16  +  W (K,N) fp32 -> wt (N,K) bf16 ----------------
// merged single launch (block-uniform branch): blocks [0,8192) convert x,
// blocks [8192, 8192+3072) transpose+convert the three weight matrices.
__global__ __launch_bounds__(256) void prep(
    const float* __restrict__ x, u16* __restrict__ xb,
    const float* __restrict__ Wq, const float* __restrict__ Wk, const float* __restrict__ Wv,
    u16* __restrict__ wtq, u16* __restrict__ wtk, u16* __restrict__ wtv){
  __shared__ float tile[32][33];
  const int id = blockIdx.x;
  if(id < 8192){
    int i = (id * 256 + threadIdx.x) * 4;
    float4 v = *(const float4*)(x + i);
    ushort4 o; o.x = f2bf(v.x); o.y = f2bf(v.y); o.z = f2bf(v.z); o.w = f2bf(v.w);
    *(ushort4*)(xb + i) = o;
  } else {
    int r3 = id - 8192;                 // 0..3071
    int z = r3 >> 10;                   // 0..2
    int rem = r3 & 1023;
    int bx = rem & 31, by = rem >> 5;
    const float* W = (z == 0) ? Wq : (z == 1) ? Wk : Wv;
    u16* wt = (z == 0) ? wtq : (z == 1) ? wtk : wtv;
    int k0 = bx * 32, n0 = by * 32;
    int tx = threadIdx.x & 31, ty = threadIdx.x >> 5;
    #pragma unroll
    for(int r = ty; r < 32; r += 8)
      tile[r][tx] = W[(size_t)(k0 + r) * DM + n0 + tx];
    __syncthreads();
    #pragma unroll
    for(int r = ty; r < 32; r += 8)
      wt[(size_t)(n0 + r) * DM + k0 + tx] = f2bf(tile[tx][r]);
  }
}

// ---------------- QKV projection GEMM (R6-verified 2-phase dbuf, ~72us) ----------------
// 128x128 tile, 4 waves; global_load_lds staging (linear dest, inverse-swizzled
// source); double-buffered: prefetch t+1 issued after the barrier, drained at the
// NEXT barrier. XCD-locality 1-D grid: XCD k owns M-tiles [8k,8k+8) (2MB of xb,
// L2-resident), weight panels iterated m-inner (panel L2-hot across its 8 blocks).
// V^T store KEY-PERMUTED (attn PV: key 16*hi+4*g+r -> pos 8*g+4*hi+r).
// Session ceiling notes: 8-phase 256^2 port (R7) and A-direct-from-L2 (R10) both
// regressed at this K=1024 shape — this 2-phase structure is the measured best.
__global__ __launch_bounds__(256) void qkv_gemm(
    const u16* __restrict__ xb,
    const u16* __restrict__ wtq, const u16* __restrict__ wtk, const u16* __restrict__ wtv,
    const float* __restrict__ bq, const float* __restrict__ bk, const float* __restrict__ bv,
    u16* __restrict__ qws, u16* __restrict__ kws, u16* __restrict__ vtws){
  __shared__ u16 sa[2][128 * 64];
  __shared__ u16 sb[2][128 * 64];
  const int id = blockIdx.x;              // 0..1535
  const int idx = id >> 3;                // 0..191 within XCD
  const int mt = (id & 7) * 8 + (idx & 7);// M-tile 0..63
  const int y  = idx >> 3;                // weight panel 0..23
  const int m0 = mt * 128;
  const int ng = y * 128;
  const int mat = ng >> 10;
  const int n0 = ng & 1023;
  const u16* wt = (mat == 0) ? wtq : (mat == 1) ? wtk : wtv;
  const float* bias = (mat == 0) ? bq : (mat == 1) ? bk : bv;
  const int tid = threadIdx.x;
  const int lane = tid & 63, w = tid >> 6;
  const int wm = (w >> 1) * 64, wn = (w & 1) * 64;
  const int wbase0 = tid & 192;   // w*64, wave-uniform

  f32x4 acc[4][4] = {};

  // stage K-tile 0 -> buf 0 (async DMA)
  #pragma unroll
  for(int p = 0; p < 4; p++){
    int base = p * 256 + wbase0;
    int idx2 = base + lane;
    int row = idx2 >> 3;
    int chs = (idx2 & 7) ^ (row & 7);
    gload16(xb + (size_t)(m0 + row) * 1024 + chs * 8, (char*)sa[0] + base * 16);
    gload16(wt + (size_t)(n0 + row) * 1024 + chs * 8, (char*)sb[0] + base * 16);
  }

  #pragma unroll 1
  for(int kt = 0; kt < 16; kt++){
    const int cur = kt & 1;
    __syncthreads();               // drains vmcnt: buf[cur] ready; buf[cur^1] readers done

    if(kt + 1 < 16){
      const int k0n = (kt + 1) * 64;
      #pragma unroll
      for(int p = 0; p < 4; p++){
        int base = p * 256 + wbase0;
        int idx2 = base + lane;
        int row = idx2 >> 3;
        int chs = (idx2 & 7) ^ (row & 7);
        gload16(xb + (size_t)(m0 + row) * 1024 + k0n + chs * 8, (char*)sa[cur ^ 1] + base * 16);
        gload16(wt + (size_t)(n0 + row) * 1024 + k0n + chs * 8, (char*)sb[cur ^ 1] + base * 16);
      }
    }

    #pragma unroll
    for(int ks = 0; ks < 2; ks++){
      short8 af[4], bfr[4];
      #pragma unroll
      for(int i = 0; i < 4; i++){
        int ra = wm + i * 16 + (lane & 15);
        int ca = ks * 64 + (lane >> 4) * 16;
        af[i] = *(const short8*)((const char*)sa[cur] + ra * 128 + (ca ^ ((ra & 7) << 4)));
        int rb = wn + i * 16 + (lane & 15);
        bfr[i] = *(const short8*)((const char*)sb[cur] + rb * 128 + (ca ^ ((rb & 7) << 4)));
      }
      __builtin_amdgcn_s_setprio(1);
      #pragma unroll
      for(int i = 0; i < 4; i++)
        #pragma unroll
        for(int j = 0; j < 4; j++)
          acc[i][j] = MFMA(af[i], bfr[j], acc[i][j]);
      __builtin_amdgcn_s_setprio(0);
    }
  }

  const float scl = (mat == 0) ? QSCALE : 1.0f;
  #pragma unroll
  for(int j = 0; j < 4; j++){
    int n = n0 + wn + j * 16 + (lane & 15);
    float bv_ = bias[n];
    int h = n >> 6, d = n & 63;
    #pragma unroll
    for(int i = 0; i < 4; i++){
      int mb = m0 + wm + i * 16 + (lane >> 4) * 4;
      int b = mb >> 11, t = mb & 2047;
      int bh = b * NH + h;
      if(mat == 2){
        // V^T store, KEY-PERMUTED within each 32-key group (attn PV b128 reads)
        ushort4 o4;
        o4.x = f2bf(acc[i][j][0] + bv_);
        o4.y = f2bf(acc[i][j][1] + bv_);
        o4.z = f2bf(acc[i][j][2] + bv_);
        o4.w = f2bf(acc[i][j][3] + bv_);
        int tp = (t & ~31) | (((t >> 2) & 3) << 3) | (((t >> 4) & 1) << 2);
        *(ushort4*)(vtws + ((size_t)bh * DK + d) * TT + tp) = o4;
      } else {
        u16* dst = (mat == 0) ? qws : kws;
        #pragma unroll
        for(int r = 0; r < 4; r++){
          u16 o = f2bf((acc[i][j][r] + bv_) * scl);
          dst[((size_t)bh * TT + t + r) * DK + d] = o;
        }
      }
    }
  }
}

// ---------------- flash attention (R6-verified: 8-wave, paired, 16 waves/CU) ----------------
// 8-wave blocks, 128 q-rows per q-tile; per-tile fixed costs amortized over 2x
// q-rows. Grid 512, bijective XCD swizzle (XCD k owns bh in [8k,8k+8), 4MB = its
// L2); pairs (x, 15-x) -> every block runs exactly 34 k-iterations (balanced —
// R2/R9 lesson: imbalance poisons occupancy). 2 blocks/CU x 8 waves = 16
// waves/CU (R8 lesson: the win condition is >=16 waves/CU). Lower 4 waves skip
// their fully-masked final k-tile. VGPR ~56 (< 64 cliff — R3 lesson).
// At ~97% of the LDS-service model — attn structural ceiling for this session
// (32x32 core R8 and dual-subtile reuse R9 both regressed).
__global__ __launch_bounds__(512) void attn(
    const u16* __restrict__ qws, const u16* __restrict__ kws, const u16* __restrict__ vtws,
    float* __restrict__ out){
  __shared__ u16 kt[2][64 * 64];    // [buf][key][d]  swizzled
  __shared__ u16 vt[2][64 * 64];    // [buf][d][key-permuted]  swizzled

  const int id = blockIdx.x;
  const int swz = (id & 7) * 64 + (id >> 3);   // bijective (512 % 8 == 0)
  const int qx = swz & 7;                      // pair index 0..7
  const int bh = swz >> 3;

  const int tid = threadIdx.x, lane = tid & 63, w = tid >> 6;   // w 0..7
  const int g = lane >> 4, ln = lane & 15;
  const int b = bh >> 4, h = bh & 15;
  const u16* kbase = kws + (size_t)bh * TT * DK;
  const u16* vbase = vtws + (size_t)bh * DK * TT;
  const int sbase = tid & 448;      // wave-uniform 16B-chunk base (HW adds lane*16)
  const int srow = tid >> 3;        // staging row 0..63
  const int schs = (tid & 7) ^ (srow & 7);     // inverse swizzle on the SOURCE

  #pragma unroll 1
  for(int qi = 0; qi < 2; qi++){
    const int qt = qi ? (15 - qx) : qx;        // 128-row q-tile 0..15
    const int q = qt * 128 + w * 16 + ln;      // this lane's q row

    // Q fragment (B-operand; pre-scaled by QSCALE): k-slots d = g*8+j (+32)
    short8 qf[2];
    {
      const u16* gq = qws + ((size_t)bh * TT + q) * DK + g * 8;
      qf[0] = *(const short8*)gq;
      qf[1] = *(const short8*)(gq + 32);
    }

    f32x4 o[4] = {};                 // O^T frags: o[i][r] = O^T[d=i*16+g*4+r][q]
    float m = -INFINITY, l = 0.f;    // l: per-lane partial sum (reduced in epilogue)

    const int nkt = 2 * qt + 2;            // block-level 64-key tiles
    const int myNkt = nkt - (w < 4 ? 1 : 0);  // lower waves: last tile fully masked

    __syncthreads();                 // prev q-tile readers done; no DMAs outstanding
    // stage k-tile 0 -> buf 0 (async DMA; 512 threads cover 64x64 in one pass)
    gload16(kbase + (size_t)srow * DK + schs * 8, (char*)kt[0] + sbase * 16);
    gload16(vbase + (size_t)srow * TT + schs * 8, (char*)vt[0] + sbase * 16);

    #pragma unroll 1
    for(int kti = 0; kti < nkt; kti++){
      const int cur = kti & 1;
      __syncthreads();               // drains vmcnt: buf[cur] ready; buf[cur^1] readers done

      // async-prefetch next tile straight into buf[cur^1] (drained at next barrier)
      if(kti + 1 < nkt){
        const int k0n = (kti + 1) * 64;
        gload16(kbase + (size_t)(k0n + srow) * DK + schs * 8, (char*)kt[cur ^ 1] + sbase * 16);
        gload16(vbase + (size_t)srow * TT + k0n + schs * 8, (char*)vt[cur ^ 1] + sbase * 16);
      }

      if(kti < myNkt){
        // S^T = K Q : s[i][r] = S[key = k0+i*16+g*4+r][q]
        f32x4 s[4];
        __builtin_amdgcn_s_setprio(1);
        #pragma unroll
        for(int i = 0; i < 4; i++){
          f32x4 c = {};
          #pragma unroll
          for(int ks = 0; ks < 2; ks++){
            int rb = i * 16 + ln;
            int cb = ks * 64 + g * 16;
            short8 kfr = *(const short8*)((const char*)kt[cur] + rb * 128 + (cb ^ ((rb & 7) << 4)));
            c = MFMA(kfr, qf[ks], c);
          }
          s[i] = c;
        }
        __builtin_amdgcn_s_setprio(0);

        if(kti == myNkt - 1){          // causal mask (this wave's diagonal tile)
          const int k0 = kti * 64;
          #pragma unroll
          for(int i = 0; i < 4; i++)
            #pragma unroll
            for(int r = 0; r < 4; r++)
              if(k0 + i * 16 + g * 4 + r > q) s[i][r] = -INFINITY;
        }

        // in-register row max (16 regs) + cross-group permlane swaps (full row = 4 groups)
        float mx0 = fmaxf(fmaxf(s[0][0], s[0][1]), fmaxf(s[0][2], s[0][3]));
        float mx1 = fmaxf(fmaxf(s[1][0], s[1][1]), fmaxf(s[1][2], s[1][3]));
        float mx2 = fmaxf(fmaxf(s[2][0], s[2][1]), fmaxf(s[2][2], s[2][3]));
        float mx3 = fmaxf(fmaxf(s[3][0], s[3][1]), fmaxf(s[3][2], s[3][3]));
        float pmax = fmaxf(fmaxf(mx0, mx1), fmaxf(mx2, mx3));
        pmax = plmax(pmax);

        // defer-max (T13): skip O-rescale when per-tile max growth <= 8 (exp2 domain)
        if(!__all(pmax <= m + 8.f)){
          float mnew = fmaxf(m, pmax);
          float alpha = EXP2(m - mnew);
          l *= alpha;
          #pragma unroll
          for(int i = 0; i < 4; i++)
            #pragma unroll
            for(int r = 0; r < 4; r++) o[i][r] *= alpha;
          m = mnew;
        }

        #pragma unroll
        for(int i = 0; i < 4; i++)
          #pragma unroll
          for(int r = 0; r < 4; r++){
            float p = EXP2(s[i][r] - m);
            s[i][r] = p; l += p;        // per-lane partial only
          }

        // pack P to bf16 B-frags in-register: pb[ks] reg j holds key kappa(g,j)+32ks
        union PU { short8 s8; unsigned w[4]; };
        PU pb[2];
        #pragma unroll
        for(int ks = 0; ks < 2; ks++){
          pb[ks].w[0] = cvtpk(s[2*ks][0],   s[2*ks][1]);
          pb[ks].w[1] = cvtpk(s[2*ks][2],   s[2*ks][3]);
          pb[ks].w[2] = cvtpk(s[2*ks+1][0], s[2*ks+1][1]);
          pb[ks].w[3] = cvtpk(s[2*ks+1][2], s[2*ks+1][3]);
        }

        // O^T += V^T P^T : key-permuted vt makes each A-frag ONE swizzled b128 read
        __builtin_amdgcn_s_setprio(1);
        #pragma unroll
        for(int i = 0; i < 4; i++){
          int dr = i * 16 + ln;
          const char* vrow = (const char*)vt[cur] + dr * 128;
          int sw = (dr & 7) << 4;
          #pragma unroll
          for(int ks = 0; ks < 2; ks++){
            short8 av = *(const short8*)(vrow + ((64 * ks + g * 16) ^ sw));
            o[i] = MFMA(av, pb[ks].s8, o[i]);
          }
        }
        __builtin_amdgcn_s_setprio(0);
      }
    }

    // epilogue: deferred l reduce, then out (B,T,DM) fp32, float4 stores
    l = plsum(l);
    float inv = 1.0f / l;
    float* orow = out + ((size_t)(b * TT + q)) * DM + h * 64 + g * 4;
    #pragma unroll
    for(int i = 0; i < 4; i++){
      float4 v4;
      v4.x = o[i][0] * inv; v4.y = o[i][1] * inv;
      v4.z = o[i][2] * inv; v4.w = o[i][3] * inv;
      *(float4*)(orow + i * 16) = v4;
    }
  }
}

extern "C" void kernel_launch(void* const* d_in, const int* in_sizes, int n_in,
                              void* d_out, int out_size, void* d_ws, size_t ws_size,
                              hipStream_t stream){
  const float* x  = (const float*)d_in[0];
  const float* Wq = (const float*)d_in[1];
  const float* bq = (const float*)d_in[2];
  const float* Wk = (const float*)d_in[3];
  const float* bk = (const float*)d_in[4];
  const float* Wv = (const float*)d_in[5];
  const float* bv = (const float*)d_in[6];
  float* out = (float*)d_out;

  char* ws = (char*)d_ws;
  u16* xb   = (u16*)(ws);                       // 16 MB  x bf16 (M,K)
  u16* wtq  = (u16*)(ws + (16u << 20));         //  2 MB  Wq^T bf16 (N,K)
  u16* wtk  = (u16*)(ws + (18u << 20));
  u16* wtv  = (u16*)(ws + (20u << 20));
  u16* qws  = (u16*)(ws + (22u << 20));         // 16 MB  Q (BH,T,DK) bf16 (pre-scaled)
  u16* kws  = (u16*)(ws + (38u << 20));         // 16 MB  K (BH,T,DK) bf16
  u16* vtws = (u16*)(ws + (54u << 20));         // 16 MB  V^T (BH,DK,T) bf16, key-permuted

  prep<<<dim3(8192 + 3072), dim3(256), 0, stream>>>(x, xb, Wq, Wk, Wv, wtq, wtk, wtv);
  qkv_gemm<<<dim3(1536), dim3(256), 0, stream>>>(xb, wtq, wtk, wtv, bq, bk, bv, qws, kws, vtws);
  attn<<<dim3(512), dim3(512), 0, stream>>>(qws, kws, vtws, out);
}